// Round 3
// baseline (321.973 us; speedup 1.0000x reference)
//
#include <hip/hip_runtime.h>

#define BINS 4096   // 16^3
#define GRID 512
#define BLOCK 1024  // 16 waves; 2 blocks/CU -> 32 waves/CU (full occupancy)

__device__ __forceinline__ int qz(float c) {
    // matches: clip((c * 15.0f).astype(int32), 0, 15); trunc == floor for c >= 0
    int q = (int)(c * 15.0f);
    q = q < 0 ? 0 : q;
    q = q > 15 ? 15 : q;
    return q;
}

__device__ __forceinline__ int bin3(float r, float g, float b) {
    return (qz(r) << 8) | (qz(g) << 4) | qz(b);
}

// Fused: per-block LDS histogram of source -> rotated global-atomic flush ->
// last block (completion counter) builds target hist in LDS and computes loss.
__global__ __launch_bounds__(BLOCK) void fused_hist_loss_kernel(
        const float* __restrict__ src, const float* __restrict__ tgt,
        unsigned int* __restrict__ g_hist, unsigned int* __restrict__ counter,
        float* __restrict__ out, int n_src, int n_tgt) {
    __shared__ unsigned int lhist[BINS];
    for (int i = threadIdx.x; i < BINS; i += BLOCK) lhist[i] = 0;
    __syncthreads();

    // ---- source histogram: 4 points per iter via 3x float4 (16 B/lane) ----
    const float4* __restrict__ src4 = (const float4*)src;
    const int n_quads = n_src >> 2;
    const int tid = blockIdx.x * BLOCK + threadIdx.x;
    const int stride = gridDim.x * BLOCK;
    for (int q = tid; q < n_quads; q += stride) {
        float4 a = src4[3 * q + 0];
        float4 b = src4[3 * q + 1];
        float4 c = src4[3 * q + 2];
        atomicAdd(&lhist[bin3(a.x, a.y, a.z)], 1u);
        atomicAdd(&lhist[bin3(a.w, b.x, b.y)], 1u);
        atomicAdd(&lhist[bin3(b.z, b.w, c.x)], 1u);
        atomicAdd(&lhist[bin3(c.y, c.z, c.w)], 1u);
    }
    if (blockIdx.x == 0) {
        int tail = n_src & 3;
        if ((int)threadIdx.x < tail) {
            int p = (n_quads << 2) + threadIdx.x;
            atomicAdd(&lhist[bin3(src[3 * p], src[3 * p + 1], src[3 * p + 2])], 1u);
        }
    }
    __syncthreads();

    // ---- flush to global, rotated start so blocks don't hot-spot same bin ----
    const int rot = (blockIdx.x * 8) & (BINS - 1);
    for (int k = threadIdx.x; k < BINS; k += BLOCK) {
        int i = (k + rot) & (BINS - 1);
        unsigned int v = lhist[i];
        if (v) atomicAdd(&g_hist[i], v);
    }

    // ---- completion counter: last block to finish computes the loss ----
    __threadfence();
    __syncthreads();
    __shared__ int is_last;
    if (threadIdx.x == 0) {
        unsigned int prev = atomicAdd(counter, 1u);
        is_last = (prev == (unsigned int)(gridDim.x - 1)) ? 1 : 0;
    }
    __syncthreads();
    if (!is_last) return;

    // ---- last block: target histogram into reused LDS ----
    for (int i = threadIdx.x; i < BINS; i += BLOCK) lhist[i] = 0;
    __syncthreads();
    const float4* __restrict__ t4 = (const float4*)tgt;
    const int tq = n_tgt >> 2;
    for (int q = threadIdx.x; q < tq; q += BLOCK) {
        float4 a = t4[3 * q + 0];
        float4 b = t4[3 * q + 1];
        float4 c = t4[3 * q + 2];
        atomicAdd(&lhist[bin3(a.x, a.y, a.z)], 1u);
        atomicAdd(&lhist[bin3(a.w, b.x, b.y)], 1u);
        atomicAdd(&lhist[bin3(b.z, b.w, c.x)], 1u);
        atomicAdd(&lhist[bin3(c.y, c.z, c.w)], 1u);
    }
    {
        int tail = n_tgt & 3;
        if ((int)threadIdx.x < tail) {
            int p = (tq << 2) + threadIdx.x;
            atomicAdd(&lhist[bin3(tgt[3 * p], tgt[3 * p + 1], tgt[3 * p + 2])], 1u);
        }
    }
    __syncthreads();

    // ---- L1 loss between normalized histograms (f64 accumulation) ----
    const double ns = (double)n_src + 1e-8;
    const double nt = (double)n_tgt + 1e-8;
    double acc = 0.0;
    for (int i = threadIdx.x; i < BINS; i += BLOCK) {
        unsigned int sv = atomicAdd(&g_hist[i], 0u);  // L2-coherent load
        double s = (double)sv / ns;
        double t = (double)lhist[i] / nt;
        acc += fabs(s - t);
    }
    for (int off = 32; off > 0; off >>= 1) acc += __shfl_down(acc, off);
    __shared__ double red[BLOCK / 64];
    const int lane = threadIdx.x & 63;
    const int wave = threadIdx.x >> 6;
    if (lane == 0) red[wave] = acc;
    __syncthreads();
    if (threadIdx.x == 0) {
        double s = 0.0;
        for (int w = 0; w < BLOCK / 64; ++w) s += red[w];
        out[0] = (float)(s / (double)BINS);
    }
}

extern "C" void kernel_launch(void* const* d_in, const int* in_sizes, int n_in,
                              void* d_out, int out_size, void* d_ws, size_t ws_size,
                              hipStream_t stream) {
    const float* src = (const float*)d_in[0];
    const float* tgt = (const float*)d_in[1];
    const int n_src = in_sizes[0] / 3;
    const int n_tgt = in_sizes[1] / 3;

    unsigned int* g_hist = (unsigned int*)d_ws;      // 4096 u32 = 16 KB
    unsigned int* counter = g_hist + BINS;           // +1 u32

    hipMemsetAsync(d_ws, 0, (BINS + 16) * sizeof(unsigned int), stream);
    fused_hist_loss_kernel<<<GRID, BLOCK, 0, stream>>>(
        src, tgt, g_hist, counter, (float*)d_out, n_src, n_tgt);
}

// Round 4
// 203.515 us; speedup vs baseline: 1.5821x; 1.5821x over previous
//
#include <hip/hip_runtime.h>

#define BINS 4096      // 16^3
#define WORDS 2048     // u16-packed: 2 bins per u32 word
#define H_GRID 2048
#define H_BLOCK 256    // 4 waves/block, 8 blocks/CU -> 32 waves/CU

__device__ __forceinline__ int qz(float c) {
    // matches: clip((c * 15.0f).astype(int32), 0, 15); trunc == floor for c >= 0
    int q = (int)(c * 15.0f);
    q = q < 0 ? 0 : q;
    q = q > 15 ? 15 : q;
    return q;
}

__device__ __forceinline__ int bin3(float r, float g, float b) {
    return (qz(r) << 8) | (qz(g) << 4) | qz(b);
}

// K1: per-block u16-packed LDS histogram, non-atomic coalesced partial flush.
// Per-block point count <= ceil(nquads/stride)*4*H_BLOCK/H_BLOCK... <= ~4100,
// so each u16 half-word can never overflow and no carry crosses halves.
__global__ __launch_bounds__(H_BLOCK) void hist_partial_kernel(
        const float* __restrict__ src, unsigned int* __restrict__ partials,
        int n_pts) {
    __shared__ unsigned int lh[WORDS];
    for (int i = threadIdx.x; i < WORDS; i += H_BLOCK) lh[i] = 0;
    __syncthreads();

    const float4* __restrict__ src4 = (const float4*)src;
    const int n_quads = n_pts >> 2;
    const int tid = blockIdx.x * H_BLOCK + threadIdx.x;
    const int stride = gridDim.x * H_BLOCK;
    for (int q = tid; q < n_quads; q += stride) {
        float4 a = src4[3 * q + 0];
        float4 b = src4[3 * q + 1];
        float4 c = src4[3 * q + 2];
        int b0 = bin3(a.x, a.y, a.z);
        int b1 = bin3(a.w, b.x, b.y);
        int b2 = bin3(b.z, b.w, c.x);
        int b3 = bin3(c.y, c.z, c.w);
        atomicAdd(&lh[b0 >> 1], 1u << ((b0 & 1) << 4));
        atomicAdd(&lh[b1 >> 1], 1u << ((b1 & 1) << 4));
        atomicAdd(&lh[b2 >> 1], 1u << ((b2 & 1) << 4));
        atomicAdd(&lh[b3 >> 1], 1u << ((b3 & 1) << 4));
    }
    if (blockIdx.x == 0) {
        int tail = n_pts & 3;
        if ((int)threadIdx.x < tail) {
            int p = (n_quads << 2) + threadIdx.x;
            int bb = bin3(src[3 * p], src[3 * p + 1], src[3 * p + 2]);
            atomicAdd(&lh[bb >> 1], 1u << ((bb & 1) << 4));
        }
    }
    __syncthreads();

    // coalesced uint4 flush: 2 passes x 256 lanes x 16 B = 8 KB
    uint4* dst = (uint4*)(partials + (size_t)blockIdx.x * WORDS);
    const uint4* lh4 = (const uint4*)lh;
#pragma unroll
    for (int p = 0; p < WORDS / (H_BLOCK * 4); ++p)
        dst[threadIdx.x + p * H_BLOCK] = lh4[threadIdx.x + p * H_BLOCK];
}

// K2: one thread per bin sums the 2048 u16 partials (coalesced rows) -> totals.
__global__ __launch_bounds__(64) void reduce_kernel(
        const unsigned int* __restrict__ partials,
        unsigned int* __restrict__ g_hist) {
    const int bin = blockIdx.x * 64 + threadIdx.x;
    const unsigned short* __restrict__ p16 = (const unsigned short*)partials;
    unsigned int s = 0;
    for (int b = 0; b < H_GRID; ++b)
        s += (unsigned int)p16[(size_t)b * BINS + bin];
    g_hist[bin] = s;
}

// K3: single block -- target hist in LDS, then L1 loss (f64, deterministic).
__global__ __launch_bounds__(1024) void loss_kernel(
        const float* __restrict__ tgt, const unsigned int* __restrict__ g_hist,
        float* __restrict__ out, int n_src, int n_tgt) {
    __shared__ unsigned int th[BINS];
    for (int i = threadIdx.x; i < BINS; i += 1024) th[i] = 0;
    __syncthreads();

    const float4* __restrict__ t4 = (const float4*)tgt;
    const int tq = n_tgt >> 2;
    for (int q = threadIdx.x; q < tq; q += 1024) {
        float4 a = t4[3 * q + 0];
        float4 b = t4[3 * q + 1];
        float4 c = t4[3 * q + 2];
        atomicAdd(&th[bin3(a.x, a.y, a.z)], 1u);
        atomicAdd(&th[bin3(a.w, b.x, b.y)], 1u);
        atomicAdd(&th[bin3(b.z, b.w, c.x)], 1u);
        atomicAdd(&th[bin3(c.y, c.z, c.w)], 1u);
    }
    {
        int tail = n_tgt & 3;
        if ((int)threadIdx.x < tail) {
            int p = (tq << 2) + threadIdx.x;
            atomicAdd(&th[bin3(tgt[3 * p], tgt[3 * p + 1], tgt[3 * p + 2])], 1u);
        }
    }
    __syncthreads();

    const double ns = (double)n_src + 1e-8;
    const double nt = (double)n_tgt + 1e-8;
    double acc = 0.0;
    for (int i = threadIdx.x; i < BINS; i += 1024)
        acc += fabs((double)g_hist[i] / ns - (double)th[i] / nt);

    for (int off = 32; off > 0; off >>= 1) acc += __shfl_down(acc, off);
    __shared__ double red[16];
    if ((threadIdx.x & 63) == 0) red[threadIdx.x >> 6] = acc;
    __syncthreads();
    if (threadIdx.x == 0) {
        double s = 0.0;
        for (int w = 0; w < 16; ++w) s += red[w];
        out[0] = (float)(s / (double)BINS);
    }
}

extern "C" void kernel_launch(void* const* d_in, const int* in_sizes, int n_in,
                              void* d_out, int out_size, void* d_ws, size_t ws_size,
                              hipStream_t stream) {
    const float* src = (const float*)d_in[0];
    const float* tgt = (const float*)d_in[1];
    const int n_src = in_sizes[0] / 3;
    const int n_tgt = in_sizes[1] / 3;

    unsigned int* partials = (unsigned int*)d_ws;            // 2048*2048 u32 = 16 MB
    unsigned int* g_hist   = partials + (size_t)H_GRID * WORDS;  // 4096 u32

    hist_partial_kernel<<<H_GRID, H_BLOCK, 0, stream>>>(src, partials, n_src);
    reduce_kernel<<<BINS / 64, 64, 0, stream>>>(partials, g_hist);
    loss_kernel<<<1, 1024, 0, stream>>>(tgt, g_hist, (float*)d_out, n_src, n_tgt);
}

// Round 5
// 153.479 us; speedup vs baseline: 2.0978x; 1.3260x over previous
//
#include <hip/hip_runtime.h>

#define BINS 4096      // 16^3
#define WORDS 2048     // u16-packed: 2 bins per u32 word
#define H_GRID 1024
#define H_BLOCK 256    // 4 waves/block, 4 blocks/CU -> 16 waves/CU
#define CHUNKS 8       // K2 row-chunks: 1024 rows / 8 = 128 rows per chunk

__device__ __forceinline__ int qz(float c) {
    // matches: clip((c * 15.0f).astype(int32), 0, 15); trunc == floor for c >= 0
    int q = (int)(c * 15.0f);
    q = q < 0 ? 0 : q;
    q = q > 15 ? 15 : q;
    return q;
}

__device__ __forceinline__ int bin3(float r, float g, float b) {
    return (qz(r) << 8) | (qz(g) << 4) | qz(b);
}

// K1: per-block u16-packed LDS histogram, non-atomic coalesced partial flush.
// Per-block point count = 8388608/1024 = 8192 (+3 tail) < 65535: no u16
// overflow, no carry across halfwords.
__global__ __launch_bounds__(H_BLOCK) void hist_partial_kernel(
        const float* __restrict__ src, unsigned int* __restrict__ partials,
        int n_pts) {
    __shared__ unsigned int lh[WORDS];
    for (int i = threadIdx.x; i < WORDS; i += H_BLOCK) lh[i] = 0;
    __syncthreads();

    const float4* __restrict__ src4 = (const float4*)src;
    const int n_quads = n_pts >> 2;
    const int tid = blockIdx.x * H_BLOCK + threadIdx.x;
    const int stride = gridDim.x * H_BLOCK;
    for (int q = tid; q < n_quads; q += stride) {
        float4 a = src4[3 * q + 0];
        float4 b = src4[3 * q + 1];
        float4 c = src4[3 * q + 2];
        int b0 = bin3(a.x, a.y, a.z);
        int b1 = bin3(a.w, b.x, b.y);
        int b2 = bin3(b.z, b.w, c.x);
        int b3 = bin3(c.y, c.z, c.w);
        atomicAdd(&lh[b0 >> 1], 1u << ((b0 & 1) << 4));
        atomicAdd(&lh[b1 >> 1], 1u << ((b1 & 1) << 4));
        atomicAdd(&lh[b2 >> 1], 1u << ((b2 & 1) << 4));
        atomicAdd(&lh[b3 >> 1], 1u << ((b3 & 1) << 4));
    }
    if (blockIdx.x == 0) {
        int tail = n_pts & 3;
        if ((int)threadIdx.x < tail) {
            int p = (n_quads << 2) + threadIdx.x;
            int bb = bin3(src[3 * p], src[3 * p + 1], src[3 * p + 2]);
            atomicAdd(&lh[bb >> 1], 1u << ((bb & 1) << 4));
        }
    }
    __syncthreads();

    // coalesced uint4 flush: 2 passes x 256 lanes x 16 B = 8 KB
    uint4* dst = (uint4*)(partials + (size_t)blockIdx.x * WORDS);
    const uint4* lh4 = (const uint4*)lh;
#pragma unroll
    for (int p = 0; p < WORDS / (H_BLOCK * 4); ++p)
        dst[threadIdx.x + p * H_BLOCK] = lh4[threadIdx.x + p * H_BLOCK];
}

// K2: parallel column-sum of the 1024 u16 partial rows.
// Grid = 16 bin-groups x 8 row-chunks = 128 blocks x 256 threads.
// Each thread sums 128 u16s for one bin (coalesced: consecutive threads read
// consecutive u16s), writes g_part[chunk][bin] non-atomically.
__global__ __launch_bounds__(256) void reduce_kernel(
        const unsigned int* __restrict__ partials,
        unsigned int* __restrict__ g_part) {
    const int bin   = (blockIdx.x & 15) * 256 + threadIdx.x;
    const int chunk = blockIdx.x >> 4;
    const int r0    = chunk * (H_GRID / CHUNKS);
    const unsigned short* __restrict__ p16 = (const unsigned short*)partials;
    unsigned int s = 0;
#pragma unroll 8
    for (int r = 0; r < H_GRID / CHUNKS; ++r)
        s += (unsigned int)p16[(size_t)(r0 + r) * BINS + bin];
    g_part[chunk * BINS + bin] = s;
}

// K3: single block -- target hist in LDS, then L1 loss (f64, deterministic).
// Source bin totals = sum of the 8 chunk-partials.
__global__ __launch_bounds__(1024) void loss_kernel(
        const float* __restrict__ tgt, const unsigned int* __restrict__ g_part,
        float* __restrict__ out, int n_src, int n_tgt) {
    __shared__ unsigned int th[BINS];
    for (int i = threadIdx.x; i < BINS; i += 1024) th[i] = 0;
    __syncthreads();

    const float4* __restrict__ t4 = (const float4*)tgt;
    const int tq = n_tgt >> 2;
    for (int q = threadIdx.x; q < tq; q += 1024) {
        float4 a = t4[3 * q + 0];
        float4 b = t4[3 * q + 1];
        float4 c = t4[3 * q + 2];
        atomicAdd(&th[bin3(a.x, a.y, a.z)], 1u);
        atomicAdd(&th[bin3(a.w, b.x, b.y)], 1u);
        atomicAdd(&th[bin3(b.z, b.w, c.x)], 1u);
        atomicAdd(&th[bin3(c.y, c.z, c.w)], 1u);
    }
    {
        int tail = n_tgt & 3;
        if ((int)threadIdx.x < tail) {
            int p = (tq << 2) + threadIdx.x;
            atomicAdd(&th[bin3(tgt[3 * p], tgt[3 * p + 1], tgt[3 * p + 2])], 1u);
        }
    }
    __syncthreads();

    const double ns = (double)n_src + 1e-8;
    const double nt = (double)n_tgt + 1e-8;
    double acc = 0.0;
    for (int i = threadIdx.x; i < BINS; i += 1024) {
        unsigned int sv = 0;
#pragma unroll
        for (int c = 0; c < CHUNKS; ++c) sv += g_part[c * BINS + i];
        acc += fabs((double)sv / ns - (double)th[i] / nt);
    }

    for (int off = 32; off > 0; off >>= 1) acc += __shfl_down(acc, off);
    __shared__ double red[16];
    if ((threadIdx.x & 63) == 0) red[threadIdx.x >> 6] = acc;
    __syncthreads();
    if (threadIdx.x == 0) {
        double s = 0.0;
        for (int w = 0; w < 16; ++w) s += red[w];
        out[0] = (float)(s / (double)BINS);
    }
}

extern "C" void kernel_launch(void* const* d_in, const int* in_sizes, int n_in,
                              void* d_out, int out_size, void* d_ws, size_t ws_size,
                              hipStream_t stream) {
    const float* src = (const float*)d_in[0];
    const float* tgt = (const float*)d_in[1];
    const int n_src = in_sizes[0] / 3;
    const int n_tgt = in_sizes[1] / 3;

    unsigned int* partials = (unsigned int*)d_ws;                 // 1024*2048 u32 = 8 MB
    unsigned int* g_part   = partials + (size_t)H_GRID * WORDS;   // 8*4096 u32 = 128 KB

    hist_partial_kernel<<<H_GRID, H_BLOCK, 0, stream>>>(src, partials, n_src);
    reduce_kernel<<<16 * CHUNKS, 256, 0, stream>>>(partials, g_part);
    loss_kernel<<<1, 1024, 0, stream>>>(tgt, g_part, (float*)d_out, n_src, n_tgt);
}